// Round 9
// baseline (150.557 us; speedup 1.0000x reference)
//
#include <hip/hip_runtime.h>
#include <hip/hip_bf16.h>

typedef __attribute__((ext_vector_type(8))) __bf16 bf16x8;
typedef __attribute__((ext_vector_type(4))) float f32x4;

#define B_M 256
#define K_D 512
#define N_C 100000
#define BN 64
#define BK 64
#define NBLK ((N_C + BN - 1) / BN)   /* 1563 */

__device__ __forceinline__ unsigned short f2bf(float x) {
  unsigned int u = __float_as_uint(x);
  u += 0x7fffu + ((u >> 16) & 1u);          // round-to-nearest-even
  return (unsigned short)(u >> 16);
}

// ---------------- kernel 1: row-normalize emb -> bf16 ff ----------------
__global__ __launch_bounds__(256) void norm_kernel(const float* __restrict__ emb,
                                                   unsigned short* __restrict__ ff) {
  const int row = blockIdx.x;
  const int t = threadIdx.x;
  float a = emb[row * K_D + t];
  float b = emb[row * K_D + t + 256];
  float ss = a * a + b * b;
  #pragma unroll
  for (int o = 32; o > 0; o >>= 1) ss += __shfl_down(ss, o, 64);
  __shared__ float red[4];
  const int wid = t >> 6, lane = t & 63;
  if (lane == 0) red[wid] = ss;
  __syncthreads();
  float tot = red[0] + red[1] + red[2] + red[3];
  float rn = 1.0f / fmaxf(sqrtf(tot), 1e-12f);
  ff[row * K_D + t]       = f2bf(a * rn);
  ff[row * K_D + t + 256] = f2bf(b * rn);
}

// ---------------- kernel 2: fused GEMM + circle-loss partial reduce ----------------
// R1's proven 2-barrier structure + T14 async-STAGE split (loads for step t+1
// issued under step t's compute). __launch_bounds__(512, 2): min 2 waves/EU ->
// VGPR budget 256, so the ~110 live regs across the barrier DON'T spill
// (R8 failed at VGPR=60 with 255 MB of scratch traffic; this is the only change).
__global__ __launch_bounds__(512, 2) void gemm_loss_kernel(const unsigned short* __restrict__ ff,
                                                           const float* __restrict__ W,
                                                           const int* __restrict__ labels,
                                                           double* __restrict__ partials) {
  __shared__ __align__(16) unsigned short As[B_M * BK];  // 32 KB, XOR-swizzled
  __shared__ __align__(16) unsigned short Bs[BN * BK];   //  8 KB, XOR-swizzled
  __shared__ int lbl[B_M];
  __shared__ double red[16];

  const int tid = threadIdx.x;
  const int wid = tid >> 6;
  const int lane = tid & 63;
  const int n0 = blockIdx.x * BN;

  if (tid < B_M) lbl[tid] = labels[tid];

  f32x4 acc[2][4] = {};

  const int wrow = wid * 32;
  const int l15 = lane & 15;
  const int lhi = lane >> 4;

  // A staging geometry: 4 chunks/thread, chunk s = it*512+tid -> row=s>>3, kc=s&7
  // W staging geometry: thread -> (col, 8-float chunk)
  const int bcol = tid >> 3;              // 0..63
  const int bk8  = tid & 7;               // 0..7
  const bool valid = (n0 + bcol) < N_C;
  const float* wp = W + (long long)(n0 + bcol) * K_D + bk8 * 8;

  uint4 areg[4];
  float4 wr0 = {0.f,0.f,0.f,0.f}, wr1 = {0.f,0.f,0.f,0.f};

  // ---- prologue: load step-0 tiles into regs ----
  #pragma unroll
  for (int it = 0; it < 4; ++it) {
    int s = it * 512 + tid;
    int row = s >> 3;
    int kc  = s & 7;
    areg[it] = *reinterpret_cast<const uint4*>(ff + row * K_D + kc * 8);
  }
  if (valid) {
    wr0 = *reinterpret_cast<const float4*>(wp);
    wr1 = *reinterpret_cast<const float4*>(wp + 4);
  }

  for (int kk = 0; kk < K_D / BK; ++kk) {
    // ---- write phase: staged regs -> LDS (swizzled) ----
    #pragma unroll
    for (int it = 0; it < 4; ++it) {
      int s = it * 512 + tid;
      int row = s >> 3;
      int kc  = s & 7;
      int off = (row * 128 + kc * 16) ^ ((row & 7) << 4);
      *reinterpret_cast<uint4*>(reinterpret_cast<char*>(As) + off) = areg[it];
    }
    {
      union { unsigned short us[8]; uint4 v; } pk;
      pk.us[0] = f2bf(wr0.x); pk.us[1] = f2bf(wr0.y); pk.us[2] = f2bf(wr0.z); pk.us[3] = f2bf(wr0.w);
      pk.us[4] = f2bf(wr1.x); pk.us[5] = f2bf(wr1.y); pk.us[6] = f2bf(wr1.z); pk.us[7] = f2bf(wr1.w);
      int off = (bcol * 128 + bk8 * 16) ^ ((bcol & 7) << 4);
      *reinterpret_cast<uint4*>(reinterpret_cast<char*>(Bs) + off) = pk.v;
    }
    __syncthreads();

    // ---- issue next step's global loads (latency hides under compute below) ----
    if (kk + 1 < K_D / BK) {
      #pragma unroll
      for (int it = 0; it < 4; ++it) {
        int s = it * 512 + tid;
        int row = s >> 3;
        int kc  = s & 7;
        areg[it] = *reinterpret_cast<const uint4*>(ff + row * K_D + (kk + 1) * BK + kc * 8);
      }
      if (valid) {
        wr0 = *reinterpret_cast<const float4*>(wp + (kk + 1) * BK);
        wr1 = *reinterpret_cast<const float4*>(wp + (kk + 1) * BK + 4);
      }
    }

    // ---- compute phase: fragments + MFMA ----
    bf16x8 afr[2][2], bfr[4][2];
    #pragma unroll
    for (int fm = 0; fm < 2; ++fm)
      #pragma unroll
      for (int ks = 0; ks < 2; ++ks) {
        int row = wrow + fm * 16 + l15;
        int off = (row * 128 + ks * 64 + lhi * 16) ^ ((row & 7) << 4);
        afr[fm][ks] = *reinterpret_cast<const bf16x8*>(reinterpret_cast<const char*>(As) + off);
      }
    #pragma unroll
    for (int fn = 0; fn < 4; ++fn)
      #pragma unroll
      for (int ks = 0; ks < 2; ++ks) {
        int col = fn * 16 + l15;
        int off = (col * 128 + ks * 64 + lhi * 16) ^ ((col & 7) << 4);
        bfr[fn][ks] = *reinterpret_cast<const bf16x8*>(reinterpret_cast<const char*>(Bs) + off);
      }
    #pragma unroll
    for (int fm = 0; fm < 2; ++fm)
      #pragma unroll
      for (int fn = 0; fn < 4; ++fn)
        #pragma unroll
        for (int ks = 0; ks < 2; ++ks)
          acc[fm][fn] = __builtin_amdgcn_mfma_f32_16x16x32_bf16(afr[fm][ks], bfr[fn][ks], acc[fm][fn], 0, 0, 0);
    __syncthreads();
  }

  // ---- fused epilogue: circle-loss terms ----
  float sn_local = 0.0f;
  double sp_local = 0.0;
  #pragma unroll
  for (int fm = 0; fm < 2; ++fm)
    #pragma unroll
    for (int fn = 0; fn < 4; ++fn)
      #pragma unroll
      for (int r = 0; r < 4; ++r) {
        int row = wrow + fm * 16 + lhi * 4 + r;   // C/D: col=lane&15, row=(lane>>4)*4+reg
        int j = n0 + fn * 16 + l15;
        float v = acc[fm][fn][r];
        if (j < N_C) {
          if (j == lbl[row]) {
            double alpha = fmax(1.25 - (double)v, 0.0);     // clamp(Op - sp, 0)
            sp_local += exp(-64.0 * alpha * ((double)v - 0.75));
          } else {
            float an = fmaxf(v + 0.25f, 0.0f);              // clamp(sn + m, 0)
            sn_local += __expf(64.0f * an * (v - 0.25f));
          }
        }
      }

  double sn_d = (double)sn_local;
  #pragma unroll
  for (int o = 32; o > 0; o >>= 1) {
    sn_d     += __shfl_down(sn_d, o, 64);
    sp_local += __shfl_down(sp_local, o, 64);
  }
  if (lane == 0) { red[wid] = sn_d; red[8 + wid] = sp_local; }
  __syncthreads();
  if (tid == 0) {
    double a = 0.0, b = 0.0;
    #pragma unroll
    for (int i = 0; i < 8; ++i) { a += red[i]; b += red[8 + i]; }
    partials[blockIdx.x] = a;          // sn partial
    partials[NBLK + blockIdx.x] = b;   // sp partial
  }
}

// ---------------- kernel 3: final reduce + log1p ----------------
__global__ __launch_bounds__(512) void finalize_kernel(const double* __restrict__ partials,
                                                       float* __restrict__ out) {
  const int t = threadIdx.x;
  double sn = 0.0, sp = 0.0;
  for (int i = t; i < NBLK; i += 512) { sn += partials[i]; sp += partials[NBLK + i]; }
  #pragma unroll
  for (int o = 32; o > 0; o >>= 1) { sn += __shfl_down(sn, o, 64); sp += __shfl_down(sp, o, 64); }
  __shared__ double red[16];
  const int wid = t >> 6, lane = t & 63;
  if (lane == 0) { red[wid] = sn; red[8 + wid] = sp; }
  __syncthreads();
  if (t == 0) {
    double a = 0.0, b = 0.0;
    for (int i = 0; i < 8; ++i) { a += red[i]; b += red[8 + i]; }
    out[0] = (float)log1p(a * b);
  }
}

extern "C" void kernel_launch(void* const* d_in, const int* in_sizes, int n_in,
                              void* d_out, int out_size, void* d_ws, size_t ws_size,
                              hipStream_t stream) {
  // inputs: 0=x (unused), 1=labels (int), 2=emb (f32), 3=W (f32)
  const int*   labels = (const int*)d_in[1];
  const float* emb    = (const float*)d_in[2];
  const float* W      = (const float*)d_in[3];
  float* out = (float*)d_out;

  unsigned short* ff = (unsigned short*)d_ws;                              // 256*512*2 = 262144 B
  double* partials = (double*)((char*)d_ws + (size_t)B_M * K_D * 2);       // 2*1563*8 B

  norm_kernel<<<B_M, 256, 0, stream>>>(emb, ff);
  gemm_loss_kernel<<<NBLK, 512, 0, stream>>>(ff, W, labels, partials);
  finalize_kernel<<<1, 512, 0, stream>>>(partials, out);
}

// Round 11
// 78.071 us; speedup vs baseline: 1.9285x; 1.9285x over previous
//
#include <hip/hip_runtime.h>
#include <hip/hip_bf16.h>

typedef __attribute__((ext_vector_type(8))) __bf16 bf16x8;
typedef __attribute__((ext_vector_type(4))) float f32x4;

#define B_M 256
#define K_D 512
#define N_C 100000
#define BM 128                        /* block M tile (M split in two) */
#define BN 64
#define BK 64
#define NSTEP (K_D / BK)              /* 8 */
#define NB_N ((N_C + BN - 1) / BN)    /* 1563 */
#define NB (2 * NB_N)                 /* 3126 blocks */

__device__ __forceinline__ unsigned short f2bf(float x) {
  unsigned int u = __float_as_uint(x);
  u += 0x7fffu + ((u >> 16) & 1u);          // round-to-nearest-even
  return (unsigned short)(u >> 16);
}

// async global->LDS, 16 B per lane, no destination registers (vmcnt-tracked)
__device__ __forceinline__ void glds16(const void* g, void* l) {
  __builtin_amdgcn_global_load_lds(
      (const __attribute__((address_space(1))) unsigned int*)g,
      (__attribute__((address_space(3))) unsigned int*)l, 16, 0, 0);
}

// ---------------- kernel 1: row-normalize emb -> bf16 ff ----------------
__global__ __launch_bounds__(256) void norm_kernel(const float* __restrict__ emb,
                                                   unsigned short* __restrict__ ff) {
  const int row = blockIdx.x;
  const int t = threadIdx.x;
  float a = emb[row * K_D + t];
  float b = emb[row * K_D + t + 256];
  float ss = a * a + b * b;
  #pragma unroll
  for (int o = 32; o > 0; o >>= 1) ss += __shfl_down(ss, o, 64);
  __shared__ float red[4];
  const int wid = t >> 6, lane = t & 63;
  if (lane == 0) red[wid] = ss;
  __syncthreads();
  float tot = red[0] + red[1] + red[2] + red[3];
  float rn = 1.0f / fmaxf(sqrtf(tot), 1e-12f);
  ff[row * K_D + t]       = f2bf(a * rn);
  ff[row * K_D + t + 256] = f2bf(b * rn);
}

// ---------------- kernel 2: fused GEMM + circle-loss partial reduce ----------------
// Single-barrier double-buffered pipeline, ZERO registers held across barriers:
//   A (L2-resident ff) -> LDS via global_load_lds (no dest regs), dbuf, swizzled source.
//   W -> 8 transient f32 regs at step top, cvt+ds_write to other B buffer at step
//   bottom; regs die before the barrier. One s_barrier + one vmcnt(0) per K-step,
//   with the whole MFMA phase between load-issue and load-use.
// BM=128 (grid 3126), LDS 48.7KB -> 3 blocks/CU; wave tile 32x32 (acc 16 AGPR).
__global__ __launch_bounds__(512) void gemm_loss_kernel(const unsigned short* __restrict__ ff,
                                                        const float* __restrict__ W,
                                                        const int* __restrict__ labels,
                                                        double* __restrict__ partials) {
  __shared__ __align__(16) unsigned short As[2][BM * BK];  // 2 x 16 KB
  __shared__ __align__(16) unsigned short Bs[2][BN * BK];  // 2 x  8 KB
  __shared__ int lbl[BM];
  __shared__ double red[16];

  const int tid = threadIdx.x;
  const int wid = tid >> 6;
  const int lane = tid & 63;
  const int l15 = lane & 15;
  const int lhi = lane >> 4;

  const int bid = blockIdx.x;
  const int nb = bid >> 1;                 // N tile index (adjacent blocks share W tile)
  const int mb = bid & 1;                  // M half
  const int n0 = nb * BN;
  const int m0 = mb * BM;

  if (tid < BM) lbl[tid] = labels[m0 + tid];

  // wave tile: mq rows [mq*32,+32), nq cols [nq*32,+32)
  const int mq = wid & 3;
  const int nq = wid >> 2;

  // W staging geometry: thread -> (col, 8-float chunk)
  const int bcol = tid >> 3;
  const int bk8  = tid & 7;
  const int jglob = n0 + bcol;
  const bool valid = jglob < N_C;
  const float* wp = W + (long long)(valid ? jglob : (N_C - 1)) * K_D + bk8 * 8;
  const int woff = (bcol * 128 + bk8 * 16) ^ ((bcol & 7) << 4);

  // glds A geometry: 2 slots/thread, slot s = it*512+tid; dest linear s*16;
  // source row = s>>3, k8 = (s&7) ^ (row&7)   (pre-swizzled source, linear dest)
  const int s0 = tid, s1 = 512 + tid;
  const int arow0 = s0 >> 3, ak0 = (s0 & 7) ^ (arow0 & 7);
  const int arow1 = s1 >> 3, ak1 = (s1 & 7) ^ (arow1 & 7);
  const unsigned short* ap0 = ff + (m0 + arow0) * K_D + ak0 * 8;
  const unsigned short* ap1 = ff + (m0 + arow1) * K_D + ak1 * 8;

  f32x4 acc[2][2] = {};

  // ---- prologue: stage step 0 ----
  {
    float4 w0 = *reinterpret_cast<const float4*>(wp);
    float4 w1 = *reinterpret_cast<const float4*>(wp + 4);
    glds16(ap0, &As[0][0] + (size_t)s0 * 8);
    glds16(ap1, &As[0][0] + (size_t)s1 * 8);
    union { unsigned short us[8]; uint4 v; } pk;
    pk.us[0] = f2bf(w0.x); pk.us[1] = f2bf(w0.y); pk.us[2] = f2bf(w0.z); pk.us[3] = f2bf(w0.w);
    pk.us[4] = f2bf(w1.x); pk.us[5] = f2bf(w1.y); pk.us[6] = f2bf(w1.z); pk.us[7] = f2bf(w1.w);
    *reinterpret_cast<uint4*>(reinterpret_cast<char*>(&Bs[0][0]) + woff) = pk.v;
    asm volatile("s_waitcnt vmcnt(0)" ::: "memory");
    asm volatile("s_waitcnt lgkmcnt(0)" ::: "memory");
    __builtin_amdgcn_s_barrier();
  }

  for (int t = 0; t < NSTEP; ++t) {
    const int cur = t & 1;
    const int nxt = cur ^ 1;
    const bool stage = (t + 1 < NSTEP);

    // ---- issue next step's loads FIRST (latency covered by compute below) ----
    float4 w0n, w1n;
    if (stage) {
      w0n = *reinterpret_cast<const float4*>(wp + (t + 1) * BK);
      w1n = *reinterpret_cast<const float4*>(wp + (t + 1) * BK + 4);
      glds16(ap0 + (t + 1) * BK, &As[nxt][0] + (size_t)s0 * 8);
      glds16(ap1 + (t + 1) * BK, &As[nxt][0] + (size_t)s1 * 8);
    }

    // ---- compute on buf[cur]: 8 ds_read + 8 MFMA, split by ks to cap reg pressure ----
    const char* ab = reinterpret_cast<const char*>(&As[cur][0]);
    const char* bb = reinterpret_cast<const char*>(&Bs[cur][0]);
    #pragma unroll
    for (int ks = 0; ks < 2; ++ks) {
      bf16x8 afr[2], bfr[2];
      #pragma unroll
      for (int fm = 0; fm < 2; ++fm) {
        int row = mq * 32 + fm * 16 + l15;
        int off = row * 128 + (((ks * 4 + lhi) ^ (row & 7)) << 4);
        afr[fm] = *reinterpret_cast<const bf16x8*>(ab + off);
      }
      #pragma unroll
      for (int fn = 0; fn < 2; ++fn) {
        int col = nq * 32 + fn * 16 + l15;
        int off = col * 128 + (((ks * 4 + lhi) ^ (col & 7)) << 4);
        bfr[fn] = *reinterpret_cast<const bf16x8*>(bb + off);
      }
      #pragma unroll
      for (int fm = 0; fm < 2; ++fm)
        #pragma unroll
        for (int fn = 0; fn < 2; ++fn)
          acc[fm][fn] = __builtin_amdgcn_mfma_f32_16x16x32_bf16(afr[fm], bfr[fn], acc[fm][fn], 0, 0, 0);
    }

    // ---- step bottom: cvt+write B(t+1), drain, ONE barrier ----
    if (stage) {
      union { unsigned short us[8]; uint4 v; } pk;
      pk.us[0] = f2bf(w0n.x); pk.us[1] = f2bf(w0n.y); pk.us[2] = f2bf(w0n.z); pk.us[3] = f2bf(w0n.w);
      pk.us[4] = f2bf(w1n.x); pk.us[5] = f2bf(w1n.y); pk.us[6] = f2bf(w1n.z); pk.us[7] = f2bf(w1n.w);
      *reinterpret_cast<uint4*>(reinterpret_cast<char*>(&Bs[nxt][0]) + woff) = pk.v;
      asm volatile("s_waitcnt vmcnt(0)" ::: "memory");   // glds A(t+1) landed
      asm volatile("s_waitcnt lgkmcnt(0)" ::: "memory"); // B(t+1) written
      __builtin_amdgcn_s_barrier();
    }
  }

  // ---- fused epilogue: circle-loss terms ----
  float sn_local = 0.0f;
  double sp_local = 0.0;
  #pragma unroll
  for (int fn = 0; fn < 2; ++fn) {
    const int col = n0 + nq * 32 + fn * 16 + l15;
    const bool cv = col < N_C;
    #pragma unroll
    for (int fm = 0; fm < 2; ++fm)
      #pragma unroll
      for (int r = 0; r < 4; ++r) {
        const int row = mq * 32 + fm * 16 + lhi * 4 + r;  // C/D: col=lane&15, row=(lane>>4)*4+reg
        float v = acc[fm][fn][r];
        if (cv) {
          if (col == lbl[row]) {
            double alpha = fmax(1.25 - (double)v, 0.0);     // clamp(Op - sp, 0)
            sp_local += exp(-64.0 * alpha * ((double)v - 0.75));
          } else {
            float an = fmaxf(v + 0.25f, 0.0f);              // clamp(sn + m, 0)
            sn_local += __expf(64.0f * an * (v - 0.25f));
          }
        }
      }
  }

  double sn_d = (double)sn_local;
  #pragma unroll
  for (int o = 32; o > 0; o >>= 1) {
    sn_d     += __shfl_down(sn_d, o, 64);
    sp_local += __shfl_down(sp_local, o, 64);
  }
  if (lane == 0) { red[wid] = sn_d; red[8 + wid] = sp_local; }
  __syncthreads();
  if (tid == 0) {
    double a = 0.0, b = 0.0;
    #pragma unroll
    for (int i = 0; i < 8; ++i) { a += red[i]; b += red[8 + i]; }
    partials[bid] = a;          // sn partial
    partials[NB + bid] = b;     // sp partial
  }
}

// ---------------- kernel 3: final reduce + log1p ----------------
__global__ __launch_bounds__(512) void finalize_kernel(const double* __restrict__ partials,
                                                       float* __restrict__ out) {
  const int t = threadIdx.x;
  double sn = 0.0, sp = 0.0;
  for (int i = t; i < NB; i += 512) { sn += partials[i]; sp += partials[NB + i]; }
  #pragma unroll
  for (int o = 32; o > 0; o >>= 1) { sn += __shfl_down(sn, o, 64); sp += __shfl_down(sp, o, 64); }
  __shared__ double red[16];
  const int wid = t >> 6, lane = t & 63;
  if (lane == 0) { red[wid] = sn; red[8 + wid] = sp; }
  __syncthreads();
  if (t == 0) {
    double a = 0.0, b = 0.0;
    for (int i = 0; i < 8; ++i) { a += red[i]; b += red[8 + i]; }
    out[0] = (float)log1p(a * b);
  }
}

extern "C" void kernel_launch(void* const* d_in, const int* in_sizes, int n_in,
                              void* d_out, int out_size, void* d_ws, size_t ws_size,
                              hipStream_t stream) {
  // inputs: 0=x (unused), 1=labels (int), 2=emb (f32), 3=W (f32)
  const int*   labels = (const int*)d_in[1];
  const float* emb    = (const float*)d_in[2];
  const float* W      = (const float*)d_in[3];
  float* out = (float*)d_out;

  unsigned short* ff = (unsigned short*)d_ws;                              // 256*512*2 = 262144 B
  double* partials = (double*)((char*)d_ws + (size_t)B_M * K_D * 2);       // 2*3126*8 B

  norm_kernel<<<B_M, 256, 0, stream>>>(emb, ff);
  gemm_loss_kernel<<<NB, 512, 0, stream>>>(ff, W, labels, partials);
  finalize_kernel<<<1, 512, 0, stream>>>(partials, out);
}

// Round 12
// 73.826 us; speedup vs baseline: 2.0393x; 1.0575x over previous
//
#include <hip/hip_runtime.h>
#include <hip/hip_bf16.h>

typedef __attribute__((ext_vector_type(8))) __bf16 bf16x8;
typedef __attribute__((ext_vector_type(16))) float f32x16;

#define B_M 256
#define K_D 512
#define N_C 100000
#define BN2 128
#define BK 64
#define NSTEP (K_D / BK)              /* 8 */
#define NB2 ((N_C + BN2 - 1) / BN2)   /* 782 */

__device__ __forceinline__ unsigned short f2bf(float x) {
  unsigned int u = __float_as_uint(x);
  u += 0x7fffu + ((u >> 16) & 1u);          // round-to-nearest-even
  return (unsigned short)(u >> 16);
}

// ---------------- kernel 1: row-normalize emb -> bf16 ff ----------------
__global__ __launch_bounds__(256) void norm_kernel(const float* __restrict__ emb,
                                                   unsigned short* __restrict__ ff) {
  const int row = blockIdx.x;
  const int t = threadIdx.x;
  float a = emb[row * K_D + t];
  float b = emb[row * K_D + t + 256];
  float ss = a * a + b * b;
  #pragma unroll
  for (int o = 32; o > 0; o >>= 1) ss += __shfl_down(ss, o, 64);
  __shared__ float red[4];
  const int wid = t >> 6, lane = t & 63;
  if (lane == 0) red[wid] = ss;
  __syncthreads();
  float tot = red[0] + red[1] + red[2] + red[3];
  float rn = 1.0f / fmaxf(sqrtf(tot), 1e-12f);
  ff[row * K_D + t]       = f2bf(a * rn);
  ff[row * K_D + t + 256] = f2bf(b * rn);
}

// ---------------- kernel 2: fused GEMM + circle-loss partial reduce ----------------
// R1's proven spill-free 2-barrier structure, upgraded to 32x32x16 MFMA:
// same fragment bytes per MFMA but 2x the MACs -> 1.55x less LDS traffic/MAC
// (the binding resource: W is L3-resident on replays, LDS ~128B/cyc/CU).
// BM=256 x BN=128 tile, 8 waves each own a 64x64 tile (2x2 of 32x32 MFMA),
// acc 4x16 f32 -> AGPRs. No registers live across barriers (anti-spill).
__global__ __launch_bounds__(512) void gemm_loss_kernel(const unsigned short* __restrict__ ff,
                                                        const float* __restrict__ W,
                                                        const int* __restrict__ labels,
                                                        double* __restrict__ partials) {
  __shared__ __align__(16) unsigned short As[B_M * BK];   // 32 KB, XOR-swizzled rows of 128B
  __shared__ __align__(16) unsigned short Bs[BN2 * BK];   // 16 KB, XOR-swizzled
  __shared__ int lbl[B_M];
  __shared__ double red[16];

  const int tid = threadIdx.x;
  const int wid = tid >> 6;
  const int lane = tid & 63;
  const int l31 = lane & 31;
  const int lk8 = lane >> 5;            // k-group within fragment
  const int mq = wid & 3;               // M strip: rows [mq*64, +64)
  const int nq = wid >> 2;              // N half:  cols [nq*64, +64)
  const int n0 = blockIdx.x * BN2;

  if (tid < B_M) lbl[tid] = labels[tid];

  // ---- W staging: 1024 slots (128 rows x 8 chunks of 8 floats); thread owns
  //      slots tid and 512+tid -> 8 lanes cover one row's 8 swizzled slots
  //      (the R1-proven 0-conflict write pattern) ----
  const int wrow0 = tid >> 3;                 // 0..63
  const int wrow1 = 64 + (tid >> 3);          // 64..127
  const int wkc = tid & 7;
  const int j0 = n0 + wrow0;
  const int j1 = n0 + wrow1;
  const float* wp0 = W + (long long)(j0 < N_C ? j0 : (N_C - 1)) * K_D + wkc * 8;
  const float* wp1 = W + (long long)(j1 < N_C ? j1 : (N_C - 1)) * K_D + wkc * 8;
  const int woff0 = wrow0 * 128 + ((wkc ^ (wrow0 & 7)) << 4);
  const int woff1 = wrow1 * 128 + ((wkc ^ (wrow1 & 7)) << 4);

  f32x16 acc[2][2] = {};

  for (int kk = 0; kk < NSTEP; ++kk) {
    if (kk) __syncthreads();
    // ---- stage A: 256x64 bf16 (4 slots/thread, R1 pattern) ----
    #pragma unroll
    for (int it = 0; it < 4; ++it) {
      int s = it * 512 + tid;
      int row = s >> 3;
      int kc  = s & 7;
      uint4 v = *reinterpret_cast<const uint4*>(ff + row * K_D + kk * BK + kc * 8);
      int off = (row * 128 + kc * 16) ^ ((row & 7) << 4);
      *reinterpret_cast<uint4*>(reinterpret_cast<char*>(As) + off) = v;
    }
    // ---- stage W: 2 slots/thread, f32 -> bf16 in-register ----
    {
      float4 a0 = *reinterpret_cast<const float4*>(wp0 + kk * BK);
      float4 a1 = *reinterpret_cast<const float4*>(wp0 + kk * BK + 4);
      float4 b0 = *reinterpret_cast<const float4*>(wp1 + kk * BK);
      float4 b1 = *reinterpret_cast<const float4*>(wp1 + kk * BK + 4);
      union { unsigned short us[8]; uint4 v; } pk;
      pk.us[0] = f2bf(a0.x); pk.us[1] = f2bf(a0.y); pk.us[2] = f2bf(a0.z); pk.us[3] = f2bf(a0.w);
      pk.us[4] = f2bf(a1.x); pk.us[5] = f2bf(a1.y); pk.us[6] = f2bf(a1.z); pk.us[7] = f2bf(a1.w);
      *reinterpret_cast<uint4*>(reinterpret_cast<char*>(Bs) + woff0) = pk.v;
      pk.us[0] = f2bf(b0.x); pk.us[1] = f2bf(b0.y); pk.us[2] = f2bf(b0.z); pk.us[3] = f2bf(b0.w);
      pk.us[4] = f2bf(b1.x); pk.us[5] = f2bf(b1.y); pk.us[6] = f2bf(b1.z); pk.us[7] = f2bf(b1.w);
      *reinterpret_cast<uint4*>(reinterpret_cast<char*>(Bs) + woff1) = pk.v;
    }
    __syncthreads();

    // ---- compute: 4 k-slices x (2x2) 32x32x16 MFMA ----
    #pragma unroll
    for (int ks = 0; ks < 4; ++ks) {
      const int c16 = ks * 2 + lk8;       // 16B chunk index within 128B row
      bf16x8 afr[2], bfr[2];
      #pragma unroll
      for (int fm = 0; fm < 2; ++fm) {
        int row = mq * 64 + fm * 32 + l31;
        int off = row * 128 + ((c16 ^ (row & 7)) << 4);
        afr[fm] = *reinterpret_cast<const bf16x8*>(reinterpret_cast<const char*>(As) + off);
      }
      #pragma unroll
      for (int fn = 0; fn < 2; ++fn) {
        int col = nq * 64 + fn * 32 + l31;
        int off = col * 128 + ((c16 ^ (col & 7)) << 4);
        bfr[fn] = *reinterpret_cast<const bf16x8*>(reinterpret_cast<const char*>(Bs) + off);
      }
      #pragma unroll
      for (int fm = 0; fm < 2; ++fm)
        #pragma unroll
        for (int fn = 0; fn < 2; ++fn)
          acc[fm][fn] = __builtin_amdgcn_mfma_f32_32x32x16_bf16(afr[fm], bfr[fn], acc[fm][fn], 0, 0, 0);
    }
  }

  // ---- fused epilogue: circle-loss terms ----
  // C/D 32x32: col = lane&31, row = (r&3) + 8*(r>>2) + 4*(lane>>5)
  float sn_local = 0.0f;
  double sp_local = 0.0;
  #pragma unroll
  for (int fn = 0; fn < 2; ++fn) {
    const int col = n0 + nq * 64 + fn * 32 + l31;
    const bool cv = col < N_C;
    #pragma unroll
    for (int fm = 0; fm < 2; ++fm)
      #pragma unroll
      for (int r = 0; r < 16; ++r) {
        const int row = mq * 64 + fm * 32 + (r & 3) + 8 * (r >> 2) + 4 * lk8;
        float v = acc[fm][fn][r];
        if (cv) {
          if (col == lbl[row]) {
            double alpha = fmax(1.25 - (double)v, 0.0);     // clamp(Op - sp, 0)
            sp_local += exp(-64.0 * alpha * ((double)v - 0.75));
          } else {
            float an = fmaxf(v + 0.25f, 0.0f);              // clamp(sn + m, 0)
            sn_local += __expf(64.0f * an * (v - 0.25f));
          }
        }
      }
  }

  double sn_d = (double)sn_local;
  #pragma unroll
  for (int o = 32; o > 0; o >>= 1) {
    sn_d     += __shfl_down(sn_d, o, 64);
    sp_local += __shfl_down(sp_local, o, 64);
  }
  if (lane == 0) { red[wid] = sn_d; red[8 + wid] = sp_local; }
  __syncthreads();
  if (tid == 0) {
    double a = 0.0, b = 0.0;
    #pragma unroll
    for (int i = 0; i < 8; ++i) { a += red[i]; b += red[8 + i]; }
    partials[blockIdx.x] = a;           // sn partial
    partials[NB2 + blockIdx.x] = b;     // sp partial
  }
}

// ---------------- kernel 3: final reduce + log1p ----------------
__global__ __launch_bounds__(512) void finalize_kernel(const double* __restrict__ partials,
                                                       float* __restrict__ out) {
  const int t = threadIdx.x;
  double sn = 0.0, sp = 0.0;
  for (int i = t; i < NB2; i += 512) { sn += partials[i]; sp += partials[NB2 + i]; }
  #pragma unroll
  for (int o = 32; o > 0; o >>= 1) { sn += __shfl_down(sn, o, 64); sp += __shfl_down(sp, o, 64); }
  __shared__ double red[16];
  const int wid = t >> 6, lane = t & 63;
  if (lane == 0) { red[wid] = sn; red[8 + wid] = sp; }
  __syncthreads();
  if (t == 0) {
    double a = 0.0, b = 0.0;
    for (int i = 0; i < 8; ++i) { a += red[i]; b += red[8 + i]; }
    out[0] = (float)log1p(a * b);
  }
}

extern "C" void kernel_launch(void* const* d_in, const int* in_sizes, int n_in,
                              void* d_out, int out_size, void* d_ws, size_t ws_size,
                              hipStream_t stream) {
  // inputs: 0=x (unused), 1=labels (int), 2=emb (f32), 3=W (f32)
  const int*   labels = (const int*)d_in[1];
  const float* emb    = (const float*)d_in[2];
  const float* W      = (const float*)d_in[3];
  float* out = (float*)d_out;

  unsigned short* ff = (unsigned short*)d_ws;                              // 256*512*2 = 262144 B
  double* partials = (double*)((char*)d_ws + (size_t)B_M * K_D * 2);       // 2*782*8 B

  norm_kernel<<<B_M, 256, 0, stream>>>(emb, ff);
  gemm_loss_kernel<<<NB2, 512, 0, stream>>>(ff, W, labels, partials);
  finalize_kernel<<<1, 512, 0, stream>>>(partials, out);
}